// Round 1
// baseline (1671.925 us; speedup 1.0000x reference)
//
#include <hip/hip_runtime.h>
#include <math.h>

#define B 8
#define L 4096
#define D 512
#define C 512          // H*DK == H*DV == 512
#define NF 4096        // FFT length == L
#define TOPK 8
#define CPB 8          // channels per workgroup in corr_fft

// ---------------------------------------------------------------------------
// GEMM: Out = A (M x 512) * W (512 x 512), f32.
// MODE 0: Out[row*512 + col]          (row-major)
// MODE 1: OutT[(b*512 + col)*4096 + t] (transposed per batch; b=row>>12)
// Tile 64x64, 256 threads, 4x4 per thread, K-chunks of 16 staged in LDS.
// ---------------------------------------------------------------------------
template <int MODE>
__global__ __launch_bounds__(256) void gemm512(const float* __restrict__ A,
                                               const float* __restrict__ W,
                                               float* __restrict__ Out) {
    __shared__ float As[16][65];
    __shared__ float Bs[16][65];
    const int tid = threadIdx.x;
    const int bm = blockIdx.x;   // 0..511
    const int bn = blockIdx.y;   // 0..7
    const int row0 = bm * 64, col0 = bn * 64;
    const int tx = tid & 15, ty = tid >> 4;

    float acc[4][4] = {};

    for (int k0 = 0; k0 < 512; k0 += 16) {
        {   // A tile: 64 rows x 16 k, float4 along k
            int ar = tid >> 2, ak = (tid & 3) << 2;
            const float4 v = *(const float4*)&A[(size_t)(row0 + ar) * 512 + k0 + ak];
            As[ak + 0][ar] = v.x; As[ak + 1][ar] = v.y;
            As[ak + 2][ar] = v.z; As[ak + 3][ar] = v.w;
        }
        {   // W tile: 16 k x 64 cols, float4 along col
            int wr = tid >> 4, wc = (tid & 15) << 2;
            const float4 v = *(const float4*)&W[(size_t)(k0 + wr) * 512 + col0 + wc];
            Bs[wr][wc + 0] = v.x; Bs[wr][wc + 1] = v.y;
            Bs[wr][wc + 2] = v.z; Bs[wr][wc + 3] = v.w;
        }
        __syncthreads();
#pragma unroll
        for (int kk = 0; kk < 16; ++kk) {
            float a0 = As[kk][ty * 4 + 0], a1 = As[kk][ty * 4 + 1];
            float a2 = As[kk][ty * 4 + 2], a3 = As[kk][ty * 4 + 3];
            float b0 = Bs[kk][tx * 4 + 0], b1 = Bs[kk][tx * 4 + 1];
            float b2 = Bs[kk][tx * 4 + 2], b3 = Bs[kk][tx * 4 + 3];
            acc[0][0] += a0 * b0; acc[0][1] += a0 * b1; acc[0][2] += a0 * b2; acc[0][3] += a0 * b3;
            acc[1][0] += a1 * b0; acc[1][1] += a1 * b1; acc[1][2] += a1 * b2; acc[1][3] += a1 * b3;
            acc[2][0] += a2 * b0; acc[2][1] += a2 * b1; acc[2][2] += a2 * b2; acc[2][3] += a2 * b3;
            acc[3][0] += a3 * b0; acc[3][1] += a3 * b1; acc[3][2] += a3 * b2; acc[3][3] += a3 * b3;
        }
        __syncthreads();
    }

    if (MODE == 0) {
#pragma unroll
        for (int r = 0; r < 4; ++r) {
            float4 v = make_float4(acc[r][0], acc[r][1], acc[r][2], acc[r][3]);
            *(float4*)&Out[(size_t)(row0 + ty * 4 + r) * 512 + col0 + tx * 4] = v;
        }
    } else {
        // transposed: for each output col, the 4 row-values are consecutive t
        int b = row0 >> 12;
        int t0 = (row0 & 4095) + ty * 4;
#pragma unroll
        for (int c = 0; c < 4; ++c) {
            float4 v = make_float4(acc[0][c], acc[1][c], acc[2][c], acc[3][c]);
            *(float4*)&Out[((size_t)(b * 512 + col0 + tx * 4 + c)) * 4096 + t0] = v;
        }
    }
}

// ---------------------------------------------------------------------------
// Stockham radix-2 FFT in LDS, N=4096, 256 threads. sign=-1 fwd, +1 inv.
// Result ends in (xr, xi) after 12 stages (even # of ping-pongs).
// Caller must __syncthreads() after filling xr/xi.
// ---------------------------------------------------------------------------
__device__ inline void fft_lds(float* xr, float* xi, float* yr, float* yi,
                               int tid, float sign) {
    float *sr = xr, *si = xi, *dr = yr, *di = yi;
    int n = NF, s = 1, ls = 0;
    while (n > 1) {
        const int m = n >> 1;
        const float theta0 = sign * 6.283185307179586f / (float)n;
#pragma unroll 1
        for (int u = tid; u < NF / 2; u += 256) {
            const int q = u & (s - 1);
            const int p = u >> ls;
            const float ang = theta0 * (float)p;
            const float wr = cosf(ang), wi = sinf(ang);
            const float ar = sr[q + s * p],       ai = si[q + s * p];
            const float br = sr[q + s * (p + m)], bi = si[q + s * (p + m)];
            dr[q + s * (2 * p)]     = ar + br;
            di[q + s * (2 * p)]     = ai + bi;
            const float tr = ar - br, ti2 = ai - bi;
            dr[q + s * (2 * p + 1)] = tr * wr - ti2 * wi;
            di[q + s * (2 * p + 1)] = tr * wi + ti2 * wr;
        }
        __syncthreads();
        float* t;
        t = sr; sr = dr; dr = t;
        t = si; si = di; di = t;
        n = m; s <<= 1; ++ls;
    }
}

// ---------------------------------------------------------------------------
// Per (b, channel-group): forward FFT of z = q + i*k, extract cross-spectrum
// Qf*conj(Kf), accumulate over CPB channels, atomicAdd into Pacc[b][f].
// ---------------------------------------------------------------------------
__global__ __launch_bounds__(256) void corr_fft(const float* __restrict__ qT,
                                                const float* __restrict__ kT,
                                                float* __restrict__ Pacc) {
    __shared__ float xr[NF], xi[NF], yr[NF], yi[NF];
    const int wg = blockIdx.x;           // 0 .. B*(C/CPB)-1 = 511
    const int b = wg / (C / CPB);
    const int cg = wg % (C / CPB);
    const int tid = threadIdx.x;

    float accR[16] = {}, accI[16] = {};

    for (int cc = 0; cc < CPB; ++cc) {
        const int c = cg * CPB + cc;
        const float* qrow = qT + ((size_t)(b * C + c)) * L;
        const float* krow = kT + ((size_t)(b * C + c)) * L;
        __syncthreads();   // protect LDS from previous iteration's readers
#pragma unroll
        for (int j = 0; j < 16; ++j) {
            const int t = j * 256 + tid;
            xr[t] = qrow[t];
            xi[t] = krow[t];
        }
        __syncthreads();
        fft_lds(xr, xi, yr, yi, tid, -1.0f);
        // fft_lds ends with a sync; xr/xi hold Z
#pragma unroll
        for (int j = 0; j < 16; ++j) {
            const int f = j * 256 + tid;
            const float ar = xr[f], ai = xi[f];
            const int fn = (NF - f) & (NF - 1);
            const float br = xr[fn], bi = xi[fn];
            // Qf = 0.5*(ar+br, ai-bi);  Kf = 0.5*(ai+bi, -(ar-br))
            const float qr_ = 0.5f * (ar + br), qi_ = 0.5f * (ai - bi);
            const float kr_ = 0.5f * (ai + bi), ki_ = -0.5f * (ar - br);
            accR[j] += qr_ * kr_ + qi_ * ki_;   // Re(Qf*conj(Kf))
            accI[j] += qi_ * kr_ - qr_ * ki_;   // Im(Qf*conj(Kf))
        }
    }
#pragma unroll
    for (int j = 0; j < 16; ++j) {
        const int f = j * 256 + tid;
        atomicAdd(&Pacc[(size_t)b * (2 * NF) + 2 * f + 0], accR[j]);
        atomicAdd(&Pacc[(size_t)b * (2 * NF) + 2 * f + 1], accI[j]);
    }
}

// ---------------------------------------------------------------------------
// Inverse FFT of accumulated cross-spectrum -> mean_value[b][tau]
// normalization: 1/NF (irfft) * 1/512 (mean over h,d)
// ---------------------------------------------------------------------------
__global__ __launch_bounds__(256) void ifft_mean(const float* __restrict__ Pacc,
                                                 float* __restrict__ mean_value) {
    __shared__ float xr[NF], xi[NF], yr[NF], yi[NF];
    const int b = blockIdx.x;
    const int tid = threadIdx.x;
#pragma unroll
    for (int j = 0; j < 16; ++j) {
        const int f = j * 256 + tid;
        xr[f] = Pacc[(size_t)b * (2 * NF) + 2 * f + 0];
        xi[f] = Pacc[(size_t)b * (2 * NF) + 2 * f + 1];
    }
    __syncthreads();
    fft_lds(xr, xi, yr, yi, tid, 1.0f);
    const float scale = 1.0f / ((float)NF * 512.0f);
#pragma unroll
    for (int j = 0; j < 16; ++j) {
        const int t = j * 256 + tid;
        mean_value[(size_t)b * NF + t] = xr[t] * scale;
    }
}

// ---------------------------------------------------------------------------
// One block: batch-mean of mean_value, iterative top-8 (tie -> lowest index,
// matching lax.top_k), per-batch softmax of the 8 selected weights.
// ---------------------------------------------------------------------------
__global__ __launch_bounds__(256) void topk_softmax(const float* __restrict__ mean_value,
                                                    int* __restrict__ idx_out,
                                                    float* __restrict__ tc_out) {
    __shared__ float mv[NF];
    __shared__ float rv[256];
    __shared__ int ri[256];
    __shared__ int sel[TOPK];
    const int tid = threadIdx.x;

    for (int j = 0; j < 16; ++j) {
        const int t = j * 256 + tid;
        float s = 0.f;
        for (int b = 0; b < B; ++b) s += mean_value[(size_t)b * NF + t];
        mv[t] = s * (1.0f / (float)B);
    }
    __syncthreads();

    for (int iter = 0; iter < TOPK; ++iter) {
        float bv = -INFINITY; int bi = NF;
        for (int j = 0; j < 16; ++j) {
            const int t = j * 256 + tid;
            const float v = mv[t];
            if (v > bv || (v == bv && t < bi)) { bv = v; bi = t; }
        }
        rv[tid] = bv; ri[tid] = bi;
        __syncthreads();
        for (int off = 128; off > 0; off >>= 1) {
            if (tid < off) {
                if (rv[tid + off] > rv[tid] ||
                    (rv[tid + off] == rv[tid] && ri[tid + off] < ri[tid])) {
                    rv[tid] = rv[tid + off]; ri[tid] = ri[tid + off];
                }
            }
            __syncthreads();
        }
        if (tid == 0) { sel[iter] = ri[0]; mv[ri[0]] = -INFINITY; }
        __syncthreads();
    }

    if (tid < B) {   // tid == batch index
        float w[TOPK];
        float mx = -INFINITY;
        for (int i = 0; i < TOPK; ++i) {
            w[i] = mean_value[(size_t)tid * NF + sel[i]];
            mx = fmaxf(mx, w[i]);
        }
        float sum = 0.f;
        for (int i = 0; i < TOPK; ++i) { w[i] = expf(w[i] - mx); sum += w[i]; }
        const float inv = 1.0f / sum;
        for (int i = 0; i < TOPK; ++i) tc_out[tid * TOPK + i] = w[i] * inv;
    }
    if (tid < TOPK) idx_out[tid] = sel[tid];
}

// ---------------------------------------------------------------------------
// context[b][t][c] = sum_i tc[b][i] * vproj[b][(t+idx[i])%L][c]
// one float4 per thread
// ---------------------------------------------------------------------------
__global__ __launch_bounds__(256) void context_kernel(const float* __restrict__ vproj,
                                                      const int* __restrict__ idx,
                                                      const float* __restrict__ tc,
                                                      float* __restrict__ ctx) {
    const size_t gid = (size_t)blockIdx.x * 256 + threadIdx.x;
    const int c4 = (int)(gid & 127);
    const int t = (int)((gid >> 7) & 4095);
    const int b = (int)(gid >> 19);

    __shared__ int sIdx[TOPK];
    __shared__ float sW[TOPK];
    if (threadIdx.x < TOPK) {
        sIdx[threadIdx.x] = idx[threadIdx.x];
        sW[threadIdx.x] = tc[b * TOPK + threadIdx.x];
    }
    __syncthreads();

    const float* vb = vproj + (size_t)b * L * C;
    float4 acc = make_float4(0.f, 0.f, 0.f, 0.f);
#pragma unroll
    for (int i = 0; i < TOPK; ++i) {
        const int row = (t + sIdx[i]) & (L - 1);
        const float4 v = *(const float4*)&vb[(size_t)row * C + c4 * 4];
        const float w = sW[i];
        acc.x += w * v.x; acc.y += w * v.y; acc.z += w * v.z; acc.w += w * v.w;
    }
    *(float4*)&ctx[gid * 4] = acc;
}

// ---------------------------------------------------------------------------
extern "C" void kernel_launch(void* const* d_in, const int* in_sizes, int n_in,
                              void* d_out, int out_size, void* d_ws, size_t ws_size,
                              hipStream_t stream) {
    const float* Q   = (const float*)d_in[0];
    const float* K   = (const float*)d_in[1];
    const float* V   = (const float*)d_in[2];
    const float* WQ  = (const float*)d_in[4];
    const float* WK  = (const float*)d_in[5];
    const float* WV  = (const float*)d_in[6];
    const float* Wfc = (const float*)d_in[7];
    float* out = (float*)d_out;

    const size_t SZ = (size_t)B * L * C;   // 16,777,216 floats
    float* qT         = (float*)d_ws;       // (B, C, L) transposed; later reused as ctx
    float* kT         = qT + SZ;            // (B, C, L)
    float* vproj      = kT + SZ;            // (B, L, C)
    float* Pacc       = vproj + SZ;         // B * NF * 2
    float* mean_value = Pacc + (size_t)B * NF * 2;  // B * NF
    float* tc         = mean_value + (size_t)B * NF; // B * 8
    int*   idx        = (int*)(tc + B * TOPK);       // 8

    dim3 gg(512, 8);
    gemm512<1><<<gg, 256, 0, stream>>>(Q, WQ, qT);
    gemm512<1><<<gg, 256, 0, stream>>>(K, WK, kT);
    gemm512<0><<<gg, 256, 0, stream>>>(V, WV, vproj);

    hipMemsetAsync(Pacc, 0, (size_t)B * NF * 2 * sizeof(float), stream);
    corr_fft<<<dim3(B * (C / CPB)), 256, 0, stream>>>(qT, kT, Pacc);
    ifft_mean<<<dim3(B), 256, 0, stream>>>(Pacc, mean_value);
    topk_softmax<<<dim3(1), 256, 0, stream>>>(mean_value, idx, tc);

    // context overwrites qT (no longer needed)
    context_kernel<<<dim3((B * L * C / 4) / 256), 256, 0, stream>>>(vproj, idx, tc, qT);
    gemm512<0><<<gg, 256, 0, stream>>>(qT, Wfc, out);
}

// Round 2
// 546.005 us; speedup vs baseline: 3.0621x; 3.0621x over previous
//
#include <hip/hip_runtime.h>
#include <math.h>

#define B 8
#define L 4096
#define C 512          // H*DK == H*DV == 512
#define NF 4096        // FFT length == L
#define TOPK 8
#define CPB 8          // channels per workgroup in corr_fft

typedef short bf16x8 __attribute__((ext_vector_type(8)));
typedef float f32x4 __attribute__((ext_vector_type(4)));

__device__ inline unsigned short f2bf(float f) {
    unsigned int u = __float_as_uint(f);
    u += 0x7FFF + ((u >> 16) & 1);          // round-to-nearest-even
    return (unsigned short)(u >> 16);
}
__device__ inline float bf2f(unsigned short h) {
    return __uint_as_float(((unsigned int)h) << 16);
}

__device__ inline void gload_lds16(const void* g, void* l) {
    __builtin_amdgcn_global_load_lds(
        (const __attribute__((address_space(1))) void*)g,
        (__attribute__((address_space(3))) void*)l, 16, 0, 0);
}

// ---------------------------------------------------------------------------
// f32 -> bf16 elementwise, 8 elems/thread, exact grid (n multiple of 2048)
// ---------------------------------------------------------------------------
__global__ __launch_bounds__(256) void cvt_bf16(const float4* __restrict__ in,
                                                uint4* __restrict__ out) {
    const int gid = blockIdx.x * 256 + threadIdx.x;
    const float4 a = in[gid * 2];
    const float4 b = in[gid * 2 + 1];
    uint4 o;
    o.x = (unsigned)f2bf(a.x) | ((unsigned)f2bf(a.y) << 16);
    o.y = (unsigned)f2bf(a.z) | ((unsigned)f2bf(a.w) << 16);
    o.z = (unsigned)f2bf(b.x) | ((unsigned)f2bf(b.y) << 16);
    o.w = (unsigned)f2bf(b.z) | ((unsigned)f2bf(b.w) << 16);
    out[gid] = o;
}

// ---------------------------------------------------------------------------
// W (512x512 f32, K x N) -> Wt (N x K, bf16), 32x32 LDS tiles
// ---------------------------------------------------------------------------
__global__ __launch_bounds__(256) void wtrans(const float* __restrict__ W,
                                              unsigned short* __restrict__ Wt) {
    __shared__ float t[32][33];
    const int tx = threadIdx.x & 31, ty = threadIdx.x >> 5;   // 32 x 8
    const int bx = blockIdx.x;   // N tile
    const int by = blockIdx.y;   // K tile
#pragma unroll
    for (int i = 0; i < 4; ++i) {
        const int k = by * 32 + ty + i * 8;
        t[ty + i * 8][tx] = W[(size_t)k * 512 + bx * 32 + tx];   // t[k][n]
    }
    __syncthreads();
#pragma unroll
    for (int i = 0; i < 4; ++i) {
        const int n = bx * 32 + ty + i * 8;
        Wt[(size_t)n * 512 + by * 32 + tx] = f2bf(t[tx][ty + i * 8]);
    }
}

// ---------------------------------------------------------------------------
// bf16 MFMA GEMM: A (32768 x 512, row-major bf16) * Bt^T (Bt is N x K bf16)
// -> Out.  TRANSOUT=1: bf16 out at [(b*512+col)*4096 + t]  (b = row>>12)
//          TRANSOUT=0: row-major out, BF16OUT selects ushort vs float.
// 128x128 tile, BK=64, 4 waves (2x2), 4x4 16x16x32 frags per wave.
// ---------------------------------------------------------------------------
template <int TRANSOUT, int BF16OUT>
__global__ __launch_bounds__(256) void gemm_mfma(const unsigned short* __restrict__ A,
                                                 const unsigned short* __restrict__ Bt,
                                                 void* __restrict__ OutP) {
    __shared__ __align__(16) unsigned short Asm[128 * 64];
    __shared__ __align__(16) unsigned short Bsm[128 * 64];
    const int tid = threadIdx.x;
    const int lane = tid & 63;
    const int w = tid >> 6;
    const int wr = w >> 1, wc = w & 1;
    const int row0 = blockIdx.x * 128;
    const int col0 = blockIdx.y * 128;

    const int ldr = tid >> 3;            // 0..31: row within 32-row group
    const int ldk = (tid & 7) << 3;      // k offset (8 bf16 = 16B per lane)
    const int ldsbase = (w << 3) * 64;   // wave's 8-row base within group (ushorts)

    f32x4 acc[4][4] = {};

    for (int k0 = 0; k0 < 512; k0 += 64) {
        __syncthreads();
#pragma unroll
        for (int i = 0; i < 4; ++i) {
            gload_lds16(A  + (size_t)(row0 + i * 32 + ldr) * 512 + k0 + ldk,
                        Asm + i * 32 * 64 + ldsbase);
            gload_lds16(Bt + (size_t)(col0 + i * 32 + ldr) * 512 + k0 + ldk,
                        Bsm + i * 32 * 64 + ldsbase);
        }
        __syncthreads();
#pragma unroll
        for (int kk = 0; kk < 2; ++kk) {
            bf16x8 af[4], bfv[4];
#pragma unroll
            for (int m = 0; m < 4; ++m)
                af[m] = *(const bf16x8*)&Asm[(wr * 64 + m * 16 + (lane & 15)) * 64 +
                                             kk * 32 + (lane >> 4) * 8];
#pragma unroll
            for (int n = 0; n < 4; ++n)
                bfv[n] = *(const bf16x8*)&Bsm[(wc * 64 + n * 16 + (lane & 15)) * 64 +
                                              kk * 32 + (lane >> 4) * 8];
#pragma unroll
            for (int m = 0; m < 4; ++m)
#pragma unroll
                for (int n = 0; n < 4; ++n)
                    acc[m][n] = __builtin_amdgcn_mfma_f32_16x16x32_bf16(
                        af[m], bfv[n], acc[m][n], 0, 0, 0);
        }
    }

    if (TRANSOUT) {
        unsigned short* Out = (unsigned short*)OutP;
        const int bidx = row0 >> 12;
        const int t0base = (row0 & 4095) + wr * 64 + (lane >> 4) * 4;
#pragma unroll
        for (int n = 0; n < 4; ++n) {
            const int col = col0 + wc * 64 + n * 16 + (lane & 15);
#pragma unroll
            for (int m = 0; m < 4; ++m) {
                const int t0 = t0base + m * 16;
                ushort4 v;
                v.x = f2bf(acc[m][n][0]);
                v.y = f2bf(acc[m][n][1]);
                v.z = f2bf(acc[m][n][2]);
                v.w = f2bf(acc[m][n][3]);
                *(ushort4*)&Out[((size_t)(bidx * 512 + col)) * 4096 + t0] = v;
            }
        }
    } else {
#pragma unroll
        for (int m = 0; m < 4; ++m) {
            const int rbase = row0 + wr * 64 + m * 16 + (lane >> 4) * 4;
#pragma unroll
            for (int n = 0; n < 4; ++n) {
                const int col = col0 + wc * 64 + n * 16 + (lane & 15);
#pragma unroll
                for (int j = 0; j < 4; ++j) {
                    if (BF16OUT)
                        ((unsigned short*)OutP)[(size_t)(rbase + j) * 512 + col] =
                            f2bf(acc[m][n][j]);
                    else
                        ((float*)OutP)[(size_t)(rbase + j) * 512 + col] = acc[m][n][j];
                }
            }
        }
    }
}

// ---------------------------------------------------------------------------
// Stockham radix-2 FFT in LDS, N=4096, 256 threads. sign=-1 fwd, +1 inv.
// ---------------------------------------------------------------------------
__device__ inline void fft_lds(float* xr, float* xi, float* yr, float* yi,
                               int tid, float sign) {
    float *sr = xr, *si = xi, *dr = yr, *di = yi;
    int n = NF, s = 1, ls = 0;
    while (n > 1) {
        const int m = n >> 1;
        const float theta0 = sign * 6.283185307179586f / (float)n;
#pragma unroll 1
        for (int u = tid; u < NF / 2; u += 256) {
            const int q = u & (s - 1);
            const int p = u >> ls;
            const float ang = theta0 * (float)p;
            const float wr = cosf(ang), wi = sinf(ang);
            const float ar = sr[q + s * p],       ai = si[q + s * p];
            const float br = sr[q + s * (p + m)], bi = si[q + s * (p + m)];
            dr[q + s * (2 * p)]     = ar + br;
            di[q + s * (2 * p)]     = ai + bi;
            const float tr = ar - br, ti2 = ai - bi;
            dr[q + s * (2 * p + 1)] = tr * wr - ti2 * wi;
            di[q + s * (2 * p + 1)] = tr * wi + ti2 * wr;
        }
        __syncthreads();
        float* t;
        t = sr; sr = dr; dr = t;
        t = si; si = di; di = t;
        n = m; s <<= 1; ++ls;
    }
}

// ---------------------------------------------------------------------------
// Per (b, channel-group): FFT of z = q + i*k (bf16 inputs), cross-spectrum
// Qf*conj(Kf) accumulated over CPB channels, atomicAdd into Pacc[b][f].
// ---------------------------------------------------------------------------
__global__ __launch_bounds__(256) void corr_fft(const unsigned short* __restrict__ qT,
                                                const unsigned short* __restrict__ kT,
                                                float* __restrict__ Pacc) {
    __shared__ float xr[NF], xi[NF], yr[NF], yi[NF];
    const int wg = blockIdx.x;
    const int b = wg / (C / CPB);
    const int cg = wg % (C / CPB);
    const int tid = threadIdx.x;

    float accR[16] = {}, accI[16] = {};

    for (int cc = 0; cc < CPB; ++cc) {
        const int c = cg * CPB + cc;
        const unsigned short* qrow = qT + ((size_t)(b * C + c)) * L;
        const unsigned short* krow = kT + ((size_t)(b * C + c)) * L;
        __syncthreads();
#pragma unroll
        for (int j = 0; j < 16; ++j) {
            const int t = j * 256 + tid;
            xr[t] = bf2f(qrow[t]);
            xi[t] = bf2f(krow[t]);
        }
        __syncthreads();
        fft_lds(xr, xi, yr, yi, tid, -1.0f);
#pragma unroll
        for (int j = 0; j < 16; ++j) {
            const int f = j * 256 + tid;
            const float ar = xr[f], ai = xi[f];
            const int fn = (NF - f) & (NF - 1);
            const float br = xr[fn], bi = xi[fn];
            const float qr_ = 0.5f * (ar + br), qi_ = 0.5f * (ai - bi);
            const float kr_ = 0.5f * (ai + bi), ki_ = -0.5f * (ar - br);
            accR[j] += qr_ * kr_ + qi_ * ki_;
            accI[j] += qi_ * kr_ - qr_ * ki_;
        }
    }
#pragma unroll
    for (int j = 0; j < 16; ++j) {
        const int f = j * 256 + tid;
        atomicAdd(&Pacc[(size_t)b * (2 * NF) + 2 * f + 0], accR[j]);
        atomicAdd(&Pacc[(size_t)b * (2 * NF) + 2 * f + 1], accI[j]);
    }
}

// ---------------------------------------------------------------------------
__global__ __launch_bounds__(256) void ifft_mean(const float* __restrict__ Pacc,
                                                 float* __restrict__ mean_value) {
    __shared__ float xr[NF], xi[NF], yr[NF], yi[NF];
    const int b = blockIdx.x;
    const int tid = threadIdx.x;
#pragma unroll
    for (int j = 0; j < 16; ++j) {
        const int f = j * 256 + tid;
        xr[f] = Pacc[(size_t)b * (2 * NF) + 2 * f + 0];
        xi[f] = Pacc[(size_t)b * (2 * NF) + 2 * f + 1];
    }
    __syncthreads();
    fft_lds(xr, xi, yr, yi, tid, 1.0f);
    const float scale = 1.0f / ((float)NF * 512.0f);
#pragma unroll
    for (int j = 0; j < 16; ++j) {
        const int t = j * 256 + tid;
        mean_value[(size_t)b * NF + t] = xr[t] * scale;
    }
}

// ---------------------------------------------------------------------------
__global__ __launch_bounds__(256) void topk_softmax(const float* __restrict__ mean_value,
                                                    int* __restrict__ idx_out,
                                                    float* __restrict__ tc_out) {
    __shared__ float mv[NF];
    __shared__ float rv[256];
    __shared__ int ri[256];
    __shared__ int sel[TOPK];
    const int tid = threadIdx.x;

    for (int j = 0; j < 16; ++j) {
        const int t = j * 256 + tid;
        float s = 0.f;
        for (int b = 0; b < B; ++b) s += mean_value[(size_t)b * NF + t];
        mv[t] = s * (1.0f / (float)B);
    }
    __syncthreads();

    for (int iter = 0; iter < TOPK; ++iter) {
        float bv = -INFINITY; int bi = NF;
        for (int j = 0; j < 16; ++j) {
            const int t = j * 256 + tid;
            const float v = mv[t];
            if (v > bv || (v == bv && t < bi)) { bv = v; bi = t; }
        }
        rv[tid] = bv; ri[tid] = bi;
        __syncthreads();
        for (int off = 128; off > 0; off >>= 1) {
            if (tid < off) {
                if (rv[tid + off] > rv[tid] ||
                    (rv[tid + off] == rv[tid] && ri[tid + off] < ri[tid])) {
                    rv[tid] = rv[tid + off]; ri[tid] = ri[tid + off];
                }
            }
            __syncthreads();
        }
        if (tid == 0) { sel[iter] = ri[0]; mv[ri[0]] = -INFINITY; }
        __syncthreads();
    }

    if (tid < B) {
        float wv[TOPK];
        float mx = -INFINITY;
        for (int i = 0; i < TOPK; ++i) {
            wv[i] = mean_value[(size_t)tid * NF + sel[i]];
            mx = fmaxf(mx, wv[i]);
        }
        float sum = 0.f;
        for (int i = 0; i < TOPK; ++i) { wv[i] = expf(wv[i] - mx); sum += wv[i]; }
        const float inv = 1.0f / sum;
        for (int i = 0; i < TOPK; ++i) tc_out[tid * TOPK + i] = wv[i] * inv;
    }
    if (tid < TOPK) idx_out[tid] = sel[tid];
}

// ---------------------------------------------------------------------------
// ctx[b][t][c] = sum_i tc[b][i] * vproj[b][(t+idx[i])%L][c]  (bf16 in/out)
// 8 channels per thread
// ---------------------------------------------------------------------------
__global__ __launch_bounds__(256) void context_bf16(const unsigned short* __restrict__ vproj,
                                                    const int* __restrict__ idx,
                                                    const float* __restrict__ tc,
                                                    unsigned short* __restrict__ ctx) {
    const size_t gid = (size_t)blockIdx.x * 256 + threadIdx.x;
    const int c8 = (int)(gid & 63);
    const int t  = (int)((gid >> 6) & 4095);
    const int b  = (int)(gid >> 18);

    __shared__ int sIdx[TOPK];
    __shared__ float sW[TOPK];
    if (threadIdx.x < TOPK) {
        sIdx[threadIdx.x] = idx[threadIdx.x];
        sW[threadIdx.x]   = tc[b * TOPK + threadIdx.x];
    }
    __syncthreads();

    const unsigned short* vb = vproj + (size_t)b * L * C;
    float a[8] = {};
#pragma unroll
    for (int i = 0; i < TOPK; ++i) {
        const int row = (t + sIdx[i]) & (L - 1);
        const uint4 v = *(const uint4*)&vb[(size_t)row * C + c8 * 8];
        const float wgt = sW[i];
        a[0] += wgt * bf2f((unsigned short)(v.x & 0xFFFF));
        a[1] += wgt * bf2f((unsigned short)(v.x >> 16));
        a[2] += wgt * bf2f((unsigned short)(v.y & 0xFFFF));
        a[3] += wgt * bf2f((unsigned short)(v.y >> 16));
        a[4] += wgt * bf2f((unsigned short)(v.z & 0xFFFF));
        a[5] += wgt * bf2f((unsigned short)(v.z >> 16));
        a[6] += wgt * bf2f((unsigned short)(v.w & 0xFFFF));
        a[7] += wgt * bf2f((unsigned short)(v.w >> 16));
    }
    uint4 o;
    o.x = (unsigned)f2bf(a[0]) | ((unsigned)f2bf(a[1]) << 16);
    o.y = (unsigned)f2bf(a[2]) | ((unsigned)f2bf(a[3]) << 16);
    o.z = (unsigned)f2bf(a[4]) | ((unsigned)f2bf(a[5]) << 16);
    o.w = (unsigned)f2bf(a[6]) | ((unsigned)f2bf(a[7]) << 16);
    *(uint4*)&ctx[gid * 8] = o;
}

// ---------------------------------------------------------------------------
extern "C" void kernel_launch(void* const* d_in, const int* in_sizes, int n_in,
                              void* d_out, int out_size, void* d_ws, size_t ws_size,
                              hipStream_t stream) {
    const float* Q   = (const float*)d_in[0];
    const float* K   = (const float*)d_in[1];
    const float* V   = (const float*)d_in[2];
    const float* WQ  = (const float*)d_in[4];
    const float* WK  = (const float*)d_in[5];
    const float* WV  = (const float*)d_in[6];
    const float* Wfc = (const float*)d_in[7];
    float* out = (float*)d_out;

    const size_t SZ = (size_t)B * L * C;          // 16,777,216 elements
    unsigned short* Qb   = (unsigned short*)d_ws; // 32 MB
    unsigned short* Kb   = Qb + SZ;               // 32 MB
    unsigned short* qTb  = Kb + SZ;               // 32 MB, (B,C,L) bf16
    unsigned short* kTb  = qTb + SZ;              // 32 MB
    unsigned short* WQt  = kTb + SZ;              // 512 KB each
    unsigned short* WKt  = WQt + 512 * 512;
    unsigned short* WVt  = WKt + 512 * 512;
    unsigned short* Wfct = WVt + 512 * 512;
    float* Pacc       = (float*)(Wfct + 512 * 512);   // B*NF*2
    float* mean_value = Pacc + (size_t)B * NF * 2;    // B*NF
    float* tc         = mean_value + (size_t)B * NF;  // B*TOPK
    int*   idx        = (int*)(tc + B * TOPK);        // TOPK

    // aliases (sequential stream execution makes these safe):
    unsigned short* Vb     = Qb;   // V cast, after GEMM-Q consumed Qb
    unsigned short* vprojb = Kb;   // V projection, after GEMM-K consumed Kb
    unsigned short* ctxb   = qTb;  // context, after corr_fft consumed qTb

    cvt_bf16<<<dim3(8192), 256, 0, stream>>>((const float4*)Q, (uint4*)Qb);
    cvt_bf16<<<dim3(8192), 256, 0, stream>>>((const float4*)K, (uint4*)Kb);
    wtrans<<<dim3(16, 16), 256, 0, stream>>>(WQ, WQt);
    wtrans<<<dim3(16, 16), 256, 0, stream>>>(WK, WKt);
    wtrans<<<dim3(16, 16), 256, 0, stream>>>(WV, WVt);
    wtrans<<<dim3(16, 16), 256, 0, stream>>>(Wfc, Wfct);

    gemm_mfma<1, 1><<<dim3(256, 4), 256, 0, stream>>>(Qb, WQt, qTb);
    gemm_mfma<1, 1><<<dim3(256, 4), 256, 0, stream>>>(Kb, WKt, kTb);

    cvt_bf16<<<dim3(8192), 256, 0, stream>>>((const float4*)V, (uint4*)Vb);
    gemm_mfma<0, 1><<<dim3(256, 4), 256, 0, stream>>>(Vb, WVt, vprojb);

    hipMemsetAsync(Pacc, 0, (size_t)B * NF * 2 * sizeof(float), stream);
    corr_fft<<<dim3(B * (C / CPB)), 256, 0, stream>>>(qTb, kTb, Pacc);
    ifft_mean<<<dim3(B), 256, 0, stream>>>(Pacc, mean_value);
    topk_softmax<<<dim3(1), 256, 0, stream>>>(mean_value, idx, tc);

    context_bf16<<<dim3(8192), 256, 0, stream>>>(vprojb, idx, tc, ctxb);
    gemm_mfma<0, 0><<<dim3(256, 4), 256, 0, stream>>>(ctxb, Wfct, out);
}